// Round 4
// baseline (363.138 us; speedup 1.0000x reference)
//
#include <hip/hip_runtime.h>
#include <hip/hip_bf16.h>
#include <stdint.h>

#define NE 40000
#define FD 768
#define ED 256
#define NB 32
#define OUTC (NE + 1)

typedef __bf16 bf16x8 __attribute__((ext_vector_type(8)));
typedef float f32x4 __attribute__((ext_vector_type(4)));
typedef unsigned short ushortx8 __attribute__((ext_vector_type(8)));

// ws layout: [0,32K) qs fp32[32][256] ; [32K,96K) n01_raw fp32[64][256] ;
//            [96K,480K) Wb bf16[256][768]
#define WS_QS 0
#define WS_N01 (32 * 1024)
#define WS_WB (96 * 1024)

__device__ __forceinline__ unsigned short f2bf(float x) {
    union { float f; unsigned u; } v; v.f = x;
    unsigned r = v.u + 0x7fffu + ((v.u >> 16) & 1u);  // RNE
    return (unsigned short)(r >> 16);
}

// ---------------------------------------------------------------------------
// Kz: zero d_out (re-poisoned 0xAA before every launch; scoring atomic-adds).
// 1280032 floats = 320008 float4.
// ---------------------------------------------------------------------------
__global__ __launch_bounds__(256) void zero_kernel(float* __restrict__ out)
{
    const int stride = gridDim.x * 256;
    for (int i = blockIdx.x * 256 + threadIdx.x; i < (NB * OUTC) / 4; i += stride)
        ((float4*)out)[i] = (float4){0.f, 0.f, 0.f, 0.f};
}

// ---------------------------------------------------------------------------
// K0: proj_W fp32 -> bf16 (256x768).
// ---------------------------------------------------------------------------
__global__ __launch_bounds__(256) void wcvt_kernel(
    const float* __restrict__ W, unsigned short* __restrict__ Wb)
{
    int i = (blockIdx.x * 256 + threadIdx.x) * 4;
    float4 v = *(const float4*)(W + i);
    ushort4 o;
    o.x = f2bf(v.x); o.y = f2bf(v.y); o.z = f2bf(v.z); o.w = f2bf(v.w);
    *(ushort4*)(Wb + i) = o;
}

// ---------------------------------------------------------------------------
// K1a: raw fp32 projection of the (<=64) entity slots. 256 blocks.
// ---------------------------------------------------------------------------
__global__ __launch_bounds__(256) void qproj_kernel(
    const float* __restrict__ ent_pkl, const float* __restrict__ W,
    const int* __restrict__ ids, const int* __restrict__ mpos,
    float* __restrict__ n01_raw)
{
    __shared__ float row[FD];
    const int bid = blockIdx.x;
    const int t = threadIdx.x;
    const int slot = bid >> 2;          // 0..63 = b*2+s
    const int dg = bid & 3;
    const int b = slot >> 1, s = slot & 1;
    const int mp = mpos[0];
    const int col = (s < mp) ? s : s + 1;
    const bool wide = (ids[1] == 0 && ids[3] == 0 && ids[5] == 0);
    const int flat = b * 3 + col;
    const int idx = wide ? ids[flat * 2] : ids[flat];
    if (!(idx >= 1 && idx <= NE)) return;  // non-entity handled in K1b

    const float* src = ent_pkl + (size_t)(idx - 1) * FD;
    for (int k = t; k < FD; k += 256) row[k] = src[k];
    __syncthreads();

    const int dim = dg * 64 + (t >> 2);
    const int p = t & 3;
    const float4* w4 = (const float4*)(W + (size_t)dim * FD);
    const float4* r4 = (const float4*)row;
    float acc = 0.f;
#pragma unroll 6
    for (int j = 0; j < 48; ++j) {
        const int k4 = p + j * 4;
        float4 a = w4[k4];
        float4 r = r4[k4];
        acc += a.x * r.x + a.y * r.y + a.z * r.z + a.w * r.w;
    }
    acc += __shfl_down(acc, 2);
    acc += __shfl_down(acc, 1);
    if (p == 0) n01_raw[slot * ED + dim] = acc;
}

// ---------------------------------------------------------------------------
// K1b: per-slot normalize, qs = sum of 2 normalized rows, score col 0.
// ---------------------------------------------------------------------------
__global__ __launch_bounds__(256) void qsum_kernel(
    const float* __restrict__ other_emb, const float* __restrict__ n01_raw,
    const int* __restrict__ ids, const int* __restrict__ mpos,
    float* __restrict__ qs, float* __restrict__ out)
{
    __shared__ float red[4];
    __shared__ float nshare;
    const int b = blockIdx.x, t = threadIdx.x;
    const int mp = mpos[0];
    const bool wide = (ids[1] == 0 && ids[3] == 0 && ids[5] == 0);

    float q = 0.f;
#pragma unroll
    for (int s = 0; s < 2; ++s) {
        const int col = (s < mp) ? s : s + 1;
        const int flat = b * 3 + col;
        const int idx = wide ? ids[flat * 2] : ids[flat];
        float v;
        if (idx >= 1 && idx <= NE) v = n01_raw[(b * 2 + s) * ED + t];
        else if (idx == 0) v = other_emb[t];
        else v = other_emb[(size_t)(idx - NE) * ED + t];

        float ss = v * v;
#pragma unroll
        for (int o = 32; o > 0; o >>= 1) ss += __shfl_down(ss, o, 64);
        if ((t & 63) == 0) red[t >> 6] = ss;
        __syncthreads();
        if (t == 0) nshare = fmaxf(sqrtf(red[0] + red[1] + red[2] + red[3]), 1e-12f);
        __syncthreads();
        q += v / nshare;
        __syncthreads();
    }
    qs[b * ED + t] = q;

    float d = fabsf(q - other_emb[t]);
#pragma unroll
    for (int o = 32; o > 0; o >>= 1) d += __shfl_down(d, o, 64);
    if ((t & 63) == 0) red[t >> 6] = d;
    __syncthreads();
    if (t == 0) out[(size_t)b * OUTC] = -(red[0] + red[1] + red[2] + red[3]);
}

// ---------------------------------------------------------------------------
// K2: B-resident GEMM + fused scoring.
// 2500 blocks x 512 thr (8 waves). Block = 32 ent rows x 128 dims
// (bid>>1 = row tile, bid&1 = col group). Wave w owns 16 cols; its B
// (16 cols x 384 k, bf16) lives in 48 VGPRs per K-half. K-loop = ds_read +
// MFMA only (no global loads, no barriers). A staged per-half into 24.5 KB
// LDS. Scoring: partial L1 sums over this block's 128 dims, atomicAdd into
// zero-initialized out. 3 blocks/CU = 24 waves/CU.
// ---------------------------------------------------------------------------
#define APITCH 392   // shorts per row (384 + 8 pad), 16B-aligned
#define SPITCH 132   // floats per row in score overlay

__global__ __launch_bounds__(512, 6) void gemm_score_kernel(
    const float* __restrict__ ent_pkl, const unsigned short* __restrict__ Wb,
    const float* __restrict__ qs, float* __restrict__ out)
{
    __shared__ __align__(16) unsigned short Asm[32 * APITCH];  // 25088 B
    float* S = (float*)Asm;  // [32][132] fp32 overlay (16896 B)

    const int t = threadIdx.x;
    const int l = t & 63;
    const int w = t >> 6;        // wave 0..7 -> 16-col strip
    const int ln15 = l & 15;
    const int lq = l >> 4;       // 0..3
    const int rt = blockIdx.x >> 1;
    const int cg = blockIdx.x & 1;
    const int r0 = rt * 32;
    const int colbase = cg * 128 + w * 16;

    f32x4 acc0 = (f32x4){0.f, 0.f, 0.f, 0.f};
    f32x4 acc1 = (f32x4){0.f, 0.f, 0.f, 0.f};

    const int srow = t >> 4;         // 0..31
    const int sseg = (t & 15) * 24;  // float offset within K-half row
    const unsigned short* bcol = Wb + (size_t)(colbase + ln15) * FD + lq * 8;

#pragma unroll
    for (int h = 0; h < 2; ++h) {
        __syncthreads();  // prior half's LDS reads complete
        // ---- stage A half: 32 rows x 384 k, fp32 -> bf16 ----
        {
            const float* ap = ent_pkl + (size_t)(r0 + srow) * FD + h * 384 + sseg;
            unsigned short* dst = Asm + srow * APITCH + sseg;
#pragma unroll
            for (int j = 0; j < 3; ++j) {
                float4 x = *(const float4*)(ap + j * 8);
                float4 y = *(const float4*)(ap + j * 8 + 4);
                ushortx8 v;
                v[0] = f2bf(x.x); v[1] = f2bf(x.y); v[2] = f2bf(x.z); v[3] = f2bf(x.w);
                v[4] = f2bf(y.x); v[5] = f2bf(y.y); v[6] = f2bf(y.z); v[7] = f2bf(y.w);
                *(ushortx8*)(dst + j * 8) = v;
            }
        }
        // ---- B half into registers (48 VGPRs) ----
        bf16x8 bfr[12];
#pragma unroll
        for (int c = 0; c < 12; ++c)
            bfr[c] = *(const bf16x8*)(bcol + h * 384 + c * 32);
        __syncthreads();
        // ---- K-loop: pure LDS + MFMA ----
#pragma unroll
        for (int c = 0; c < 12; ++c) {
            bf16x8 a0 = *(const bf16x8*)(Asm + ln15 * APITCH + c * 32 + lq * 8);
            bf16x8 a1 = *(const bf16x8*)(Asm + (16 + ln15) * APITCH + c * 32 + lq * 8);
            acc0 = __builtin_amdgcn_mfma_f32_16x16x32_bf16(a0, bfr[c], acc0, 0, 0, 0);
            acc1 = __builtin_amdgcn_mfma_f32_16x16x32_bf16(a1, bfr[c], acc1, 0, 0, 0);
        }
    }

    // ---- scoring over this block's 128 dims ----
    __syncthreads();  // all A reads done; reuse LDS as S
    // C/D layout: col = lane&15, row = lq*4 + reg (acc1 rows +16)
#pragma unroll
    for (int r = 0; r < 4; ++r) {
        S[(lq * 4 + r) * SPITCH + w * 16 + ln15] = acc0[r];
        S[(16 + lq * 4 + r) * SPITCH + w * 16 + ln15] = acc1[r];
    }
    __syncthreads();

    const int sb = t & 31;           // batch
    const int e2 = (t >> 5) * 2;     // local entities e2, e2+1
    const float* q = qs + sb * ED + cg * 128;
    const float* x0 = S + e2 * SPITCH;
    const float* x1 = x0 + SPITCH;
    float s0 = 0.f, s1 = 0.f;
#pragma unroll 8
    for (int d = 0; d < 128; d += 4) {
        float4 qv = *(const float4*)(q + d);
        float4 a = *(const float4*)(x0 + d);
        float4 b = *(const float4*)(x1 + d);
        s0 += fabsf(qv.x - a.x) + fabsf(qv.y - a.y) + fabsf(qv.z - a.z) + fabsf(qv.w - a.w);
        s1 += fabsf(qv.x - b.x) + fabsf(qv.y - b.y) + fabsf(qv.z - b.z) + fabsf(qv.w - b.w);
    }
    atomicAdd(out + (size_t)sb * OUTC + 1 + r0 + e2, -s0);
    atomicAdd(out + (size_t)sb * OUTC + 1 + r0 + e2 + 1, -s1);
}

extern "C" void kernel_launch(void* const* d_in, const int* in_sizes, int n_in,
                              void* d_out, int out_size, void* d_ws, size_t ws_size,
                              hipStream_t stream) {
    const float* ent_pkl = (const float*)d_in[0];
    const float* other_emb = (const float*)d_in[1];
    const float* proj_W = (const float*)d_in[2];
    const int* ids = (const int*)d_in[3];
    const int* mpos = (const int*)d_in[4];
    float* out = (float*)d_out;

    float* qs = (float*)((char*)d_ws + WS_QS);
    float* n01_raw = (float*)((char*)d_ws + WS_N01);
    unsigned short* Wb = (unsigned short*)((char*)d_ws + WS_WB);

    zero_kernel<<<625, 256, 0, stream>>>(out);
    wcvt_kernel<<<(ED * FD) / 1024, 256, 0, stream>>>(proj_W, Wb);
    qproj_kernel<<<64 * 4, 256, 0, stream>>>(ent_pkl, proj_W, ids, mpos, n01_raw);
    qsum_kernel<<<NB, 256, 0, stream>>>(other_emb, n01_raw, ids, mpos, qs, out);
    gemm_score_kernel<<<(NE / 32) * 2, 512, 0, stream>>>(ent_pkl, Wb, qs, out);
}

// Round 5
// 273.960 us; speedup vs baseline: 1.3255x; 1.3255x over previous
//
#include <hip/hip_runtime.h>
#include <hip/hip_bf16.h>
#include <stdint.h>

#define NE 40000
#define FD 768
#define ED 256
#define NB 32
#define OUTC (NE + 1)

typedef __bf16 bf16x8 __attribute__((ext_vector_type(8)));
typedef float f32x4 __attribute__((ext_vector_type(4)));
typedef unsigned short ushortx8 __attribute__((ext_vector_type(8)));

// ws layout: [0,32K) qs fp32[32][256] ; [32K,96K) n01_raw fp32[64][256] ;
//            [96K,480K) Wb bf16[256][768]
#define WS_QS 0
#define WS_N01 (32 * 1024)
#define WS_WB (96 * 1024)

__device__ __forceinline__ unsigned short f2bf(float x) {
    union { float f; unsigned u; } v; v.f = x;
    unsigned r = v.u + 0x7fffu + ((v.u >> 16) & 1u);  // RNE
    return (unsigned short)(r >> 16);
}

// ---------------------------------------------------------------------------
// Kprep: blocks 0..191 convert proj_W fp32->bf16; blocks 192..255 project
// one query slot each (raw fp32 dot, 256 dims x K=768).
// ---------------------------------------------------------------------------
__global__ __launch_bounds__(256) void prep_kernel(
    const float* __restrict__ ent_pkl, const float* __restrict__ W,
    const int* __restrict__ ids, const int* __restrict__ mpos,
    unsigned short* __restrict__ Wb, float* __restrict__ n01_raw)
{
    const int bid = blockIdx.x;
    const int t = threadIdx.x;

    if (bid < 192) {  // wcvt: 192 blocks x 1024 floats
        int i = bid * 1024 + t * 4;
        float4 v = *(const float4*)(W + i);
        ushort4 o;
        o.x = f2bf(v.x); o.y = f2bf(v.y); o.z = f2bf(v.z); o.w = f2bf(v.w);
        *(ushort4*)(Wb + i) = o;
        return;
    }

    // qproj: one block per slot
    __shared__ float row[FD];
    const int slot = bid - 192;         // 0..63 = b*2+s
    const int b = slot >> 1, s = slot & 1;
    const int mp = mpos[0];
    const int col = (s < mp) ? s : s + 1;
    const bool wide = (ids[1] == 0 && ids[3] == 0 && ids[5] == 0);
    const int flat = b * 3 + col;
    const int idx = wide ? ids[flat * 2] : ids[flat];
    if (!(idx >= 1 && idx <= NE)) return;  // non-entity handled in qsum

    const float* src = ent_pkl + (size_t)(idx - 1) * FD;
    for (int k = t; k < FD; k += 256) row[k] = src[k];
    __syncthreads();

    const float4* w4 = (const float4*)(W + (size_t)t * FD);
    const float4* r4 = (const float4*)row;
    float a0 = 0.f, a1 = 0.f, a2 = 0.f, a3 = 0.f;
#pragma unroll 2
    for (int k4 = 0; k4 < FD / 4; k4 += 4) {
        float4 w0 = w4[k4 + 0], r0 = r4[k4 + 0];
        float4 w1 = w4[k4 + 1], r1 = r4[k4 + 1];
        float4 w2 = w4[k4 + 2], r2 = r4[k4 + 2];
        float4 w3 = w4[k4 + 3], r3 = r4[k4 + 3];
        a0 += w0.x * r0.x + w0.y * r0.y + w0.z * r0.z + w0.w * r0.w;
        a1 += w1.x * r1.x + w1.y * r1.y + w1.z * r1.z + w1.w * r1.w;
        a2 += w2.x * r2.x + w2.y * r2.y + w2.z * r2.z + w2.w * r2.w;
        a3 += w3.x * r3.x + w3.y * r3.y + w3.z * r3.z + w3.w * r3.w;
    }
    n01_raw[slot * ED + t] = (a0 + a1) + (a2 + a3);
}

// ---------------------------------------------------------------------------
// K1b: per-slot normalize, qs = sum of 2 normalized rows, score col 0.
// ---------------------------------------------------------------------------
__global__ __launch_bounds__(256) void qsum_kernel(
    const float* __restrict__ other_emb, const float* __restrict__ n01_raw,
    const int* __restrict__ ids, const int* __restrict__ mpos,
    float* __restrict__ qs, float* __restrict__ out)
{
    __shared__ float red[4];
    __shared__ float nshare;
    const int b = blockIdx.x, t = threadIdx.x;
    const int mp = mpos[0];
    const bool wide = (ids[1] == 0 && ids[3] == 0 && ids[5] == 0);

    float q = 0.f;
#pragma unroll
    for (int s = 0; s < 2; ++s) {
        const int col = (s < mp) ? s : s + 1;
        const int flat = b * 3 + col;
        const int idx = wide ? ids[flat * 2] : ids[flat];
        float v;
        if (idx >= 1 && idx <= NE) v = n01_raw[(b * 2 + s) * ED + t];
        else if (idx == 0) v = other_emb[t];
        else v = other_emb[(size_t)(idx - NE) * ED + t];

        float ss = v * v;
#pragma unroll
        for (int o = 32; o > 0; o >>= 1) ss += __shfl_down(ss, o, 64);
        if ((t & 63) == 0) red[t >> 6] = ss;
        __syncthreads();
        if (t == 0) nshare = fmaxf(sqrtf(red[0] + red[1] + red[2] + red[3]), 1e-12f);
        __syncthreads();
        q += v / nshare;
        __syncthreads();
    }
    qs[b * ED + t] = q;

    float d = fabsf(q - other_emb[t]);
#pragma unroll
    for (int o = 32; o > 0; o >>= 1) d += __shfl_down(d, o, 64);
    if ((t & 63) == 0) red[t >> 6] = d;
    __syncthreads();
    if (t == 0) out[(size_t)b * OUTC] = -(red[0] + red[1] + red[2] + red[3]);
}

// ---------------------------------------------------------------------------
// K2: 1250 blocks x 512 thr (8 waves). Block = 32 entity rows x ALL 256 dims.
// A (32x768 bf16, pitch 776) staged once in LDS. Wave w owns 16-col strip
// w*16 within each cg-half (cg*128). B register-resident per (cg,h) quarter.
// GEMM loop: ds_read_b128 + MFMA only, no barriers. Scoring: qs staged in
// LDS (Lq, pitch 260), C dumped per half into LDS S (pitch 132); per-thread
// (batch, entity-pair) partial sums in regs; direct stores, no atomics.
// ---------------------------------------------------------------------------
#define APITCH 776   // shorts per A row
#define SPITCH 132   // floats per S row
#define QPITCH 260   // floats per Lq row

__global__ __launch_bounds__(512, 6) void gemm_score_kernel(
    const float* __restrict__ ent_pkl, const unsigned short* __restrict__ Wb,
    const float* __restrict__ qs, float* __restrict__ out)
{
    __shared__ __align__(16) unsigned char smem[50176];
    unsigned short* Asm = (unsigned short*)smem;        // [32][776] bf16
    float* Lq = (float*)smem;                            // [32][260] fp32
    float* S = (float*)(smem + 33280);                   // [32][132] fp32

    const int t = threadIdx.x;
    const int l = t & 63;
    const int w = t >> 6;        // wave 0..7 -> 16-col strip within half
    const int ln15 = l & 15;
    const int lq = l >> 4;       // 0..3
    const int r0 = blockIdx.x * 32;

    // ---- stage A: 32 rows x 768, fp32 -> bf16, once ----
    {
        const int srow = t >> 4;          // 0..31
        const int seg = (t & 15) * 48;    // floats
        const float* ap = ent_pkl + (size_t)(r0 + srow) * FD + seg;
        unsigned short* dst = Asm + srow * APITCH + seg;
#pragma unroll
        for (int j = 0; j < 6; ++j) {
            float4 x = *(const float4*)(ap + j * 8);
            float4 y = *(const float4*)(ap + j * 8 + 4);
            ushortx8 v;
            v[0] = f2bf(x.x); v[1] = f2bf(x.y); v[2] = f2bf(x.z); v[3] = f2bf(x.w);
            v[4] = f2bf(y.x); v[5] = f2bf(y.y); v[6] = f2bf(y.z); v[7] = f2bf(y.w);
            *(ushortx8*)(dst + j * 8) = v;
        }
    }
    __syncthreads();

    f32x4 acc[2][2];
#pragma unroll
    for (int cg = 0; cg < 2; ++cg)
#pragma unroll
        for (int s = 0; s < 2; ++s) acc[cg][s] = (f32x4){0.f, 0.f, 0.f, 0.f};

    // ---- GEMM: barrier-free ----
    const unsigned short* a0p = Asm + ln15 * APITCH + lq * 8;
    const unsigned short* a1p = a0p + 16 * APITCH;
#pragma unroll
    for (int cg = 0; cg < 2; ++cg) {
        const unsigned short* bcol =
            Wb + (size_t)(cg * 128 + w * 16 + ln15) * FD + lq * 8;
#pragma unroll
        for (int h = 0; h < 2; ++h) {
            bf16x8 bfr[12];
#pragma unroll
            for (int c = 0; c < 12; ++c)
                bfr[c] = *(const bf16x8*)(bcol + (h * 12 + c) * 32);
#pragma unroll
            for (int c = 0; c < 12; ++c) {
                const int off = (h * 12 + c) * 32;
                bf16x8 a0 = *(const bf16x8*)(a0p + off);
                bf16x8 a1 = *(const bf16x8*)(a1p + off);
                acc[cg][0] = __builtin_amdgcn_mfma_f32_16x16x32_bf16(a0, bfr[c], acc[cg][0], 0, 0, 0);
                acc[cg][1] = __builtin_amdgcn_mfma_f32_16x16x32_bf16(a1, bfr[c], acc[cg][1], 0, 0, 0);
            }
        }
    }
    __syncthreads();  // all A reads done; LDS becomes Lq + S

    // ---- fill Lq (qs -> LDS) + dump S for cg=0 ----
    {
        const int b = t >> 4;
        const int dseg = (t & 15) * 16;
        const float* src = qs + b * ED + dseg;
        float* dst = Lq + b * QPITCH + dseg;
#pragma unroll
        for (int j = 0; j < 4; ++j)
            *(float4*)(dst + j * 4) = *(const float4*)(src + j * 4);
    }
#pragma unroll
    for (int s = 0; s < 2; ++s)
#pragma unroll
        for (int r = 0; r < 4; ++r)
            S[(s * 16 + lq * 4 + r) * SPITCH + w * 16 + ln15] = acc[0][s][r];
    __syncthreads();

    // ---- scoring ----
    const int sb = t & 31;          // batch
    const int ep = t >> 5;          // entity pair -> rows 2ep, 2ep+1
    float s0 = 0.f, s1 = 0.f;

#pragma unroll
    for (int cg = 0; cg < 2; ++cg) {
        if (cg == 1) {
            __syncthreads();  // score cg0 reads complete
#pragma unroll
            for (int s = 0; s < 2; ++s)
#pragma unroll
                for (int r = 0; r < 4; ++r)
                    S[(s * 16 + lq * 4 + r) * SPITCH + w * 16 + ln15] = acc[1][s][r];
            __syncthreads();
        }
        const float* q = Lq + sb * QPITCH + cg * 128;
        const float* x0 = S + (2 * ep) * SPITCH;
        const float* x1 = x0 + SPITCH;
#pragma unroll 8
        for (int d = 0; d < 128; d += 4) {
            float4 qv = *(const float4*)(q + d);
            float4 a = *(const float4*)(x0 + d);
            float4 b = *(const float4*)(x1 + d);
            s0 += fabsf(qv.x - a.x) + fabsf(qv.y - a.y) + fabsf(qv.z - a.z) + fabsf(qv.w - a.w);
            s1 += fabsf(qv.x - b.x) + fabsf(qv.y - b.y) + fabsf(qv.z - b.z) + fabsf(qv.w - b.w);
        }
    }
    float* op = out + (size_t)sb * OUTC + 1 + r0 + 2 * ep;
    op[0] = -s0;
    op[1] = -s1;
}

extern "C" void kernel_launch(void* const* d_in, const int* in_sizes, int n_in,
                              void* d_out, int out_size, void* d_ws, size_t ws_size,
                              hipStream_t stream) {
    const float* ent_pkl = (const float*)d_in[0];
    const float* other_emb = (const float*)d_in[1];
    const float* proj_W = (const float*)d_in[2];
    const int* ids = (const int*)d_in[3];
    const int* mpos = (const int*)d_in[4];
    float* out = (float*)d_out;

    float* qs = (float*)((char*)d_ws + WS_QS);
    float* n01_raw = (float*)((char*)d_ws + WS_N01);
    unsigned short* Wb = (unsigned short*)((char*)d_ws + WS_WB);

    prep_kernel<<<256, 256, 0, stream>>>(ent_pkl, proj_W, ids, mpos, Wb, n01_raw);
    qsum_kernel<<<NB, 256, 0, stream>>>(other_emb, n01_raw, ids, mpos, qs, out);
    gemm_score_kernel<<<NE / 32, 512, 0, stream>>>(ent_pkl, Wb, qs, out);
}

// Round 6
// 260.520 us; speedup vs baseline: 1.3939x; 1.0516x over previous
//
#include <hip/hip_runtime.h>
#include <hip/hip_bf16.h>
#include <stdint.h>

#define NE 40000
#define FD 768
#define ED 256
#define NB 32
#define OUTC (NE + 1)

typedef __bf16 bf16x8 __attribute__((ext_vector_type(8)));
typedef float f32x4 __attribute__((ext_vector_type(4)));
typedef float f32x16 __attribute__((ext_vector_type(16)));

// ws layout: [0,32K) qs fp32[32][256] ; [32K,96K) n01_raw fp32[64][256] ;
//            [96K,480K) Wb bf16[256][768]
#define WS_QS 0
#define WS_N01 (32 * 1024)
#define WS_WB (96 * 1024)

__device__ __forceinline__ float bflo(unsigned u) {
    union { unsigned u; float f; } v; v.u = u << 16; return v.f;
}
__device__ __forceinline__ float bfhi(unsigned u) {
    union { unsigned u; float f; } v; v.u = u & 0xffff0000u; return v.f;
}

// ---------------------------------------------------------------------------
// Kprep: blocks 0..191 convert proj_W fp32->bf16; blocks 192..255 project
// one query slot each (raw fp32 dot, 256 dims x K=768).
// ---------------------------------------------------------------------------
__global__ __launch_bounds__(256) void prep_kernel(
    const float* __restrict__ ent_pkl, const float* __restrict__ W,
    const int* __restrict__ ids, const int* __restrict__ mpos,
    __bf16* __restrict__ Wb, float* __restrict__ n01_raw)
{
    const int bid = blockIdx.x;
    const int t = threadIdx.x;

    if (bid < 192) {  // wcvt: 192 blocks x 1024 floats
        int i = bid * 1024 + t * 4;
        float4 v = *(const float4*)(W + i);
        __bf16 o[4] = {(__bf16)v.x, (__bf16)v.y, (__bf16)v.z, (__bf16)v.w};
        *(ushort4*)(Wb + i) = *(const ushort4*)o;
        return;
    }

    __shared__ float row[FD];
    const int slot = bid - 192;         // 0..63 = b*2+s
    const int b = slot >> 1, s = slot & 1;
    const int mp = mpos[0];
    const int col = (s < mp) ? s : s + 1;
    const bool wide = (ids[1] == 0 && ids[3] == 0 && ids[5] == 0);
    const int flat = b * 3 + col;
    const int idx = wide ? ids[flat * 2] : ids[flat];
    if (!(idx >= 1 && idx <= NE)) return;  // non-entity handled in qsum

    const float* src = ent_pkl + (size_t)(idx - 1) * FD;
    for (int k = t; k < FD; k += 256) row[k] = src[k];
    __syncthreads();

    const float4* w4 = (const float4*)(W + (size_t)t * FD);
    const float4* r4 = (const float4*)row;
    float a0 = 0.f, a1 = 0.f, a2 = 0.f, a3 = 0.f;
#pragma unroll 2
    for (int k4 = 0; k4 < FD / 4; k4 += 4) {
        float4 w0 = w4[k4 + 0], r0 = r4[k4 + 0];
        float4 w1 = w4[k4 + 1], r1 = r4[k4 + 1];
        float4 w2 = w4[k4 + 2], r2 = r4[k4 + 2];
        float4 w3 = w4[k4 + 3], r3 = r4[k4 + 3];
        a0 += w0.x * r0.x + w0.y * r0.y + w0.z * r0.z + w0.w * r0.w;
        a1 += w1.x * r1.x + w1.y * r1.y + w1.z * r1.z + w1.w * r1.w;
        a2 += w2.x * r2.x + w2.y * r2.y + w2.z * r2.z + w2.w * r2.w;
        a3 += w3.x * r3.x + w3.y * r3.y + w3.z * r3.z + w3.w * r3.w;
    }
    n01_raw[slot * ED + t] = (a0 + a1) + (a2 + a3);
}

// ---------------------------------------------------------------------------
// K1b: per-slot normalize, qs = sum of 2 normalized rows, score col 0.
// ---------------------------------------------------------------------------
__global__ __launch_bounds__(256) void qsum_kernel(
    const float* __restrict__ other_emb, const float* __restrict__ n01_raw,
    const int* __restrict__ ids, const int* __restrict__ mpos,
    float* __restrict__ qs, float* __restrict__ out)
{
    __shared__ float red[4];
    __shared__ float nshare;
    const int b = blockIdx.x, t = threadIdx.x;
    const int mp = mpos[0];
    const bool wide = (ids[1] == 0 && ids[3] == 0 && ids[5] == 0);

    float q = 0.f;
#pragma unroll
    for (int s = 0; s < 2; ++s) {
        const int col = (s < mp) ? s : s + 1;
        const int flat = b * 3 + col;
        const int idx = wide ? ids[flat * 2] : ids[flat];
        float v;
        if (idx >= 1 && idx <= NE) v = n01_raw[(b * 2 + s) * ED + t];
        else if (idx == 0) v = other_emb[t];
        else v = other_emb[(size_t)(idx - NE) * ED + t];

        float ss = v * v;
#pragma unroll
        for (int o = 32; o > 0; o >>= 1) ss += __shfl_down(ss, o, 64);
        if ((t & 63) == 0) red[t >> 6] = ss;
        __syncthreads();
        if (t == 0) nshare = fmaxf(sqrtf(red[0] + red[1] + red[2] + red[3]), 1e-12f);
        __syncthreads();
        q += v / nshare;
        __syncthreads();
    }
    qs[b * ED + t] = q;

    float d = fabsf(q - other_emb[t]);
#pragma unroll
    for (int o = 32; o > 0; o >>= 1) d += __shfl_down(d, o, 64);
    if ((t & 63) == 0) red[t >> 6] = d;
    __syncthreads();
    if (t == 0) out[(size_t)b * OUTC] = -(red[0] + red[1] + red[2] + red[3]);
}

// ---------------------------------------------------------------------------
// K2: 625 blocks x 512 thr (8 waves). Block = 64 entity rows x 256 dims.
// GEMM: mfma_f32_32x32x16_bf16; wave w owns cols 32w..32w+31, two 32-row
// strips. A staged in 2 K-halves (64x384 bf16, XOR-swizzled octets, 48 KB).
// C -> S bf16[64][264]. Scoring: lane = entity (64), wave = 4 batches whose
// q rows are wave-uniform (SGPR s_load); per 4-dim chunk: ONE b64 LDS read.
// Stores: lane=entity -> 256 B coalesced runs per batch. No atomics.
// ---------------------------------------------------------------------------
#define SP 264   // bf16 per S row

__global__ __launch_bounds__(512, 6) void gemm_score_kernel(
    const float* __restrict__ ent_pkl, const __bf16* __restrict__ Wb,
    const float* __restrict__ qs, float* __restrict__ out)
{
    __shared__ __align__(16) unsigned char smem[49152];
    __bf16* Asm = (__bf16*)smem;     // [64][384] per K-half, XOR-swizzled
    __bf16* Sb = (__bf16*)smem;      // [64][264] overlay after GEMM

    const int t = threadIdx.x;
    const int l = t & 63;
    const int w = t >> 6;        // wave 0..7 -> cols 32w..32w+31
    const int m31 = l & 31;
    const int dh = l >> 5;       // k-half within octet pair
    const int e0 = blockIdx.x * 64;

    f32x16 acc0 = {0.f}, acc1 = {0.f};
#pragma unroll
    for (int i = 0; i < 16; ++i) { acc0[i] = 0.f; acc1[i] = 0.f; }

    const int srow = t >> 3;      // 0..63 staging row
    const int sseg = t & 7;       // 8 segs x 48 floats
    const int ssw = srow & 7;
    const __bf16* brow = Wb + (size_t)(32 * w + m31) * FD + dh * 8;
    const __bf16* arow0 = Asm + m31 * 384;
    const __bf16* arow1 = Asm + (32 + m31) * 384;
    const int asw = m31 & 7;

#pragma unroll
    for (int h = 0; h < 2; ++h) {
        __syncthreads();  // prior half's A reads complete
        // ---- stage A half: 64 rows x 384 k, fp32 -> bf16, octet-swizzled ----
        {
            const float* ap = ent_pkl + (size_t)(e0 + srow) * FD + h * 384 + sseg * 48;
            __bf16* dst = Asm + srow * 384;
#pragma unroll
            for (int j = 0; j < 6; ++j) {
                float4 x = *(const float4*)(ap + j * 8);
                float4 y = *(const float4*)(ap + j * 8 + 4);
                bf16x8 v;
                v[0] = (__bf16)x.x; v[1] = (__bf16)x.y; v[2] = (__bf16)x.z; v[3] = (__bf16)x.w;
                v[4] = (__bf16)y.x; v[5] = (__bf16)y.y; v[6] = (__bf16)y.z; v[7] = (__bf16)y.w;
                *(bf16x8*)(dst + ((sseg * 6 + j) ^ ssw) * 8) = v;
            }
        }
        __syncthreads();
        // ---- 24 k-chunks: 1 B global load + 2 A LDS reads + 2 MFMA ----
#pragma unroll 4
        for (int c = 0; c < 24; ++c) {
            bf16x8 bv = *(const bf16x8*)(brow + h * 384 + c * 16);
            const int oct = (2 * c + dh) ^ asw;
            bf16x8 a0 = *(const bf16x8*)(arow0 + oct * 8);
            bf16x8 a1 = *(const bf16x8*)(arow1 + oct * 8);
            acc0 = __builtin_amdgcn_mfma_f32_32x32x16_bf16(a0, bv, acc0, 0, 0, 0);
            acc1 = __builtin_amdgcn_mfma_f32_32x32x16_bf16(a1, bv, acc1, 0, 0, 0);
        }
    }

    // ---- dump C -> S bf16[64][264]; row=(reg&3)+8*(reg>>2)+4*dh, col=32w+m31
    __syncthreads();
#pragma unroll
    for (int r = 0; r < 16; ++r) {
        const int erow = (r & 3) + 8 * (r >> 2) + 4 * dh;
        Sb[erow * SP + 32 * w + m31] = (__bf16)acc0[r];
        Sb[(32 + erow) * SP + 32 * w + m31] = (__bf16)acc1[r];
    }
    __syncthreads();

    // ---- scoring: lane = entity l; wave handles batches 4*wu..4*wu+3 ----
    const int wu = __builtin_amdgcn_readfirstlane(w);
    const float4* q0 = (const float4*)(qs + (4 * wu + 0) * ED);
    const float4* q1 = (const float4*)(qs + (4 * wu + 1) * ED);
    const float4* q2 = (const float4*)(qs + (4 * wu + 2) * ED);
    const float4* q3 = (const float4*)(qs + (4 * wu + 3) * ED);
    const unsigned* xrow = (const unsigned*)(Sb + l * SP);

    float s0 = 0.f, s1 = 0.f, s2 = 0.f, s3 = 0.f;
#pragma unroll 2
    for (int c = 0; c < 64; ++c) {
        uint2 xd = *(const uint2*)(xrow + c * 2);
        float x0 = bflo(xd.x), x1 = bfhi(xd.x);
        float x2 = bflo(xd.y), x3 = bfhi(xd.y);
        float4 qa = q0[c];
        float4 qb = q1[c];
        float4 qc = q2[c];
        float4 qd = q3[c];
        s0 += fabsf(qa.x - x0) + fabsf(qa.y - x1) + fabsf(qa.z - x2) + fabsf(qa.w - x3);
        s1 += fabsf(qb.x - x0) + fabsf(qb.y - x1) + fabsf(qb.z - x2) + fabsf(qb.w - x3);
        s2 += fabsf(qc.x - x0) + fabsf(qc.y - x1) + fabsf(qc.z - x2) + fabsf(qc.w - x3);
        s3 += fabsf(qd.x - x0) + fabsf(qd.y - x1) + fabsf(qd.z - x2) + fabsf(qd.w - x3);
    }
    float* ob = out + 1 + e0 + l;
    ob[(size_t)(4 * wu + 0) * OUTC] = -s0;
    ob[(size_t)(4 * wu + 1) * OUTC] = -s1;
    ob[(size_t)(4 * wu + 2) * OUTC] = -s2;
    ob[(size_t)(4 * wu + 3) * OUTC] = -s3;
}

extern "C" void kernel_launch(void* const* d_in, const int* in_sizes, int n_in,
                              void* d_out, int out_size, void* d_ws, size_t ws_size,
                              hipStream_t stream) {
    const float* ent_pkl = (const float*)d_in[0];
    const float* other_emb = (const float*)d_in[1];
    const float* proj_W = (const float*)d_in[2];
    const int* ids = (const int*)d_in[3];
    const int* mpos = (const int*)d_in[4];
    float* out = (float*)d_out;

    float* qs = (float*)((char*)d_ws + WS_QS);
    float* n01_raw = (float*)((char*)d_ws + WS_N01);
    __bf16* Wb = (__bf16*)((char*)d_ws + WS_WB);

    prep_kernel<<<256, 256, 0, stream>>>(ent_pkl, proj_W, ids, mpos, Wb, n01_raw);
    qsum_kernel<<<NB, 256, 0, stream>>>(other_emb, n01_raw, ids, mpos, qs, out);
    gemm_score_kernel<<<NE / 64, 512, 0, stream>>>(ent_pkl, Wb, qs, out);
}